// Round 1
// baseline (6919.926 us; speedup 1.0000x reference)
//
#include <hip/hip_runtime.h>

#define L_  6
#define E_  384
#define T_  256
#define H_  6
#define D_  64
#define V_  65
#define FF_ 1536
#define B_  64
#define BT_ (B_*T_)    // 16384 rows
#define HD_ 384        // H*D

// ---------------------------------------------------------------------------
// Embedding: h[b,t,:] = tok_emb[x[b,t]] + pos_emb[t]
// ---------------------------------------------------------------------------
__global__ void embed_kernel(const int* __restrict__ x, const float* __restrict__ tok,
                             const float* __restrict__ pos, float* __restrict__ h) {
  const int total4 = BT_ * E_ / 4;
  for (int i = blockIdx.x * blockDim.x + threadIdx.x; i < total4;
       i += gridDim.x * blockDim.x) {
    const int flat = i << 2;
    const int row  = flat / E_;
    const int e    = flat - row * E_;
    const int id   = x[row];
    const float4 a = *reinterpret_cast<const float4*>(tok + id * E_ + e);
    const float4 p = *reinterpret_cast<const float4*>(pos + (row & (T_ - 1)) * E_ + e);
    float4 o;
    o.x = a.x + p.x; o.y = a.y + p.y; o.z = a.z + p.z; o.w = a.w + p.w;
    *reinterpret_cast<float4*>(h + flat) = o;
  }
}

// ---------------------------------------------------------------------------
// LayerNorm, one wave (64 lanes) per row of E_=384 (=64*6) elements.
// DDOF=1 for ln1/ln2 (unbiased var), DDOF=0 for final ln.
// ---------------------------------------------------------------------------
template<int DDOF>
__global__ void ln_kernel(const float* __restrict__ in, float* __restrict__ out,
                          const float* __restrict__ g, const float* __restrict__ b) {
  const int wave = threadIdx.x >> 6;
  const int lane = threadIdx.x & 63;
  const int row  = (blockIdx.x << 2) + wave;
  const float* p = in + (size_t)row * E_;
  float xv[6];
  float sum = 0.f, sq = 0.f;
#pragma unroll
  for (int i = 0; i < 6; ++i) {
    xv[i] = p[lane + (i << 6)];
    sum += xv[i];
    sq  += xv[i] * xv[i];
  }
#pragma unroll
  for (int off = 32; off > 0; off >>= 1) {
    sum += __shfl_xor(sum, off);
    sq  += __shfl_xor(sq, off);
  }
  const float mean = sum * (1.f / E_);
  const float var  = (sq - E_ * mean * mean) * (1.f / (E_ - DDOF));
  const float inv  = rsqrtf(var + 1e-5f);
  float* o = out + (size_t)row * E_;
#pragma unroll
  for (int i = 0; i < 6; ++i) {
    const int c = lane + (i << 6);
    o[c] = g[c] * (xv[i] - mean) * inv + b[c];
  }
}

// ---------------------------------------------------------------------------
// fp32 tiled GEMM: C[M,N] = A[M,K] @ B[K,N] (+bias[n]) (+R same shape) (ReLU)
// BM=BN=64, BK=16, 256 threads, 4x4 per thread. M % 64 == 0, K % 16 == 0.
// N may be ragged (bounds-checked on B loads and C stores).
// ---------------------------------------------------------------------------
template<bool HAS_BIAS, bool HAS_RES, bool RELU>
__global__ __launch_bounds__(256)
void gemm_f32(const float* __restrict__ A, const float* __restrict__ B,
              const float* __restrict__ bias, const float* __restrict__ R,
              float* __restrict__ C, int M, int N, int K) {
  __shared__ float As[16][64];   // [k][m] (A transposed in LDS)
  __shared__ float Bs[16][64];   // [k][n]
  const int row0 = blockIdx.y << 6;
  const int col0 = blockIdx.x << 6;
  const int tid  = threadIdx.x;
  const int tx   = tid & 15;     // 16 cols of threads
  const int ty   = tid >> 4;     // 16 rows of threads
  float acc[4][4] = {};

  for (int k0 = 0; k0 < K; k0 += 16) {
    {  // A tile: 64 rows x 16 k. thread -> row=tid/4, k=(tid%4)*4
      const int m  = tid >> 2;
      const int kk = (tid & 3) << 2;
      const float4 a4 = *reinterpret_cast<const float4*>(
          A + (size_t)(row0 + m) * K + k0 + kk);
      As[kk + 0][m] = a4.x; As[kk + 1][m] = a4.y;
      As[kk + 2][m] = a4.z; As[kk + 3][m] = a4.w;
    }
    {  // B tile: 16 k x 64 n. thread -> k=tid/16, n=(tid%16)*4
      const int kk = tid >> 4;
      const int n  = (tid & 15) << 2;
      const float* bp = B + (size_t)(k0 + kk) * N + col0 + n;
      float4 b4;
      if (col0 + n + 3 < N) {
        b4 = *reinterpret_cast<const float4*>(bp);
      } else {
        b4.x = (col0 + n + 0 < N) ? bp[0] : 0.f;
        b4.y = (col0 + n + 1 < N) ? bp[1] : 0.f;
        b4.z = (col0 + n + 2 < N) ? bp[2] : 0.f;
        b4.w = (col0 + n + 3 < N) ? bp[3] : 0.f;
      }
      *reinterpret_cast<float4*>(&Bs[kk][n]) = b4;
    }
    __syncthreads();
#pragma unroll
    for (int kk = 0; kk < 16; ++kk) {
      const float4 a4 = *reinterpret_cast<const float4*>(&As[kk][ty << 2]);
      const float4 b4 = *reinterpret_cast<const float4*>(&Bs[kk][tx << 2]);
      const float av[4] = {a4.x, a4.y, a4.z, a4.w};
      const float bv[4] = {b4.x, b4.y, b4.z, b4.w};
#pragma unroll
      for (int i = 0; i < 4; ++i)
#pragma unroll
        for (int j = 0; j < 4; ++j)
          acc[i][j] = fmaf(av[i], bv[j], acc[i][j]);
    }
    __syncthreads();
  }

#pragma unroll
  for (int i = 0; i < 4; ++i) {
    const int row = row0 + (ty << 2) + i;
    const int col = col0 + (tx << 2);
    float val[4];
#pragma unroll
    for (int j = 0; j < 4; ++j) {
      val[j] = acc[i][j];
      if (HAS_BIAS && col + j < N) val[j] += bias[col + j];
    }
    if (col + 3 < N) {
      if (HAS_RES) {
        const float4 r4 = *reinterpret_cast<const float4*>(R + (size_t)row * N + col);
        val[0] += r4.x; val[1] += r4.y; val[2] += r4.z; val[3] += r4.w;
      }
      if (RELU) {
#pragma unroll
        for (int j = 0; j < 4; ++j) val[j] = fmaxf(val[j], 0.f);
      }
      float4 o; o.x = val[0]; o.y = val[1]; o.z = val[2]; o.w = val[3];
      *reinterpret_cast<float4*>(C + (size_t)row * N + col) = o;
    } else {
#pragma unroll
      for (int j = 0; j < 4; ++j) {
        if (col + j < N) {
          float v = val[j];
          if (HAS_RES) v += R[(size_t)row * N + col + j];
          if (RELU) v = fmaxf(v, 0.f);
          C[(size_t)row * N + col + j] = v;
        }
      }
    }
  }
}

// ---------------------------------------------------------------------------
// Causal attention: one block per (b, head), one thread per query position.
// Online softmax over K/V tiles of 64 staged in LDS.
// q,k,v,att layout: [BT, HD] with head h at columns h*64..h*64+63.
// ---------------------------------------------------------------------------
__global__ __launch_bounds__(256)
void attn_kernel(const float* __restrict__ q, const float* __restrict__ k,
                 const float* __restrict__ v, float* __restrict__ att) {
  const int bh = blockIdx.x;
  const int b  = bh / H_;
  const int hh = bh - b * H_;
  const int t  = threadIdx.x;  // query index 0..255

  __shared__ float Kt[64][64];
  __shared__ float Vt[64][64];

  float qr[64];
  {
    const float* qp = q + ((size_t)(b * T_ + t) * HD_) + hh * D_;
#pragma unroll
    for (int d = 0; d < 64; d += 4) {
      const float4 f = *reinterpret_cast<const float4*>(qp + d);
      qr[d] = f.x; qr[d + 1] = f.y; qr[d + 2] = f.z; qr[d + 3] = f.w;
    }
  }

  float m = -1e30f, s = 0.f;
  float acc[64];
#pragma unroll
  for (int d = 0; d < 64; ++d) acc[d] = 0.f;

  for (int tile = 0; tile < 4; ++tile) {
    __syncthreads();
    {  // cooperative load: thread -> row=tid/4, 16-col slab=(tid%4)*16
      const int r = threadIdx.x >> 2;
      const int c = (threadIdx.x & 3) << 4;
      const size_t src = ((size_t)(b * T_ + (tile << 6) + r) * HD_) + hh * D_ + c;
#pragma unroll
      for (int i = 0; i < 16; i += 4) {
        *reinterpret_cast<float4*>(&Kt[r][c + i]) =
            *reinterpret_cast<const float4*>(k + src + i);
        *reinterpret_cast<float4*>(&Vt[r][c + i]) =
            *reinterpret_cast<const float4*>(v + src + i);
      }
    }
    __syncthreads();

    const int rel  = t - (tile << 6);
    const int jmax = rel > 63 ? 63 : rel;
    for (int j = 0; j <= jmax; ++j) {
      float dot = 0.f;
#pragma unroll
      for (int d = 0; d < 64; ++d) dot = fmaf(qr[d], Kt[j][d], dot);
      dot *= 0.125f;  // D^-0.5
      const float nm = fmaxf(m, dot);
      const float w  = __expf(dot - nm);
      const float f  = __expf(m - nm);
      s = s * f + w;
#pragma unroll
      for (int d = 0; d < 64; ++d) acc[d] = fmaf(acc[d], f, w * Vt[j][d]);
      m = nm;
    }
  }

  const float inv = 1.f / s;
  float* ap = att + ((size_t)(b * T_ + t) * HD_) + hh * D_;
#pragma unroll
  for (int d = 0; d < 64; d += 4) {
    float4 o;
    o.x = acc[d] * inv; o.y = acc[d + 1] * inv;
    o.z = acc[d + 2] * inv; o.w = acc[d + 3] * inv;
    *reinterpret_cast<float4*>(ap + d) = o;
  }
}

// ---------------------------------------------------------------------------
extern "C" void kernel_launch(void* const* d_in, const int* in_sizes, int n_in,
                              void* d_out, int out_size, void* d_ws, size_t ws_size,
                              hipStream_t stream) {
  const int*   x    = (const int*)  d_in[0];
  const float* tok  = (const float*)d_in[1];
  const float* pos  = (const float*)d_in[2];
  const float* Wq   = (const float*)d_in[3];
  const float* Wk   = (const float*)d_in[4];
  const float* Wv   = (const float*)d_in[5];
  const float* Wpr  = (const float*)d_in[6];
  const float* bpr  = (const float*)d_in[7];
  const float* W1   = (const float*)d_in[8];
  const float* b1   = (const float*)d_in[9];
  const float* W2   = (const float*)d_in[10];
  const float* b2   = (const float*)d_in[11];
  const float* ln1g = (const float*)d_in[12];
  const float* ln1b = (const float*)d_in[13];
  const float* ln2g = (const float*)d_in[14];
  const float* ln2b = (const float*)d_in[15];
  const float* lnfg = (const float*)d_in[16];
  const float* lnfb = (const float*)d_in[17];
  const float* Wlm  = (const float*)d_in[18];
  const float* blm  = (const float*)d_in[19];
  float* out = (float*)d_out;

  const size_t NE = (size_t)BT_ * E_;  // 6,291,456
  float* ws  = (float*)d_ws;
  float* h   = ws;            // [BT,E]
  float* hn  = ws + NE;       // [BT,E]
  float* qb  = ws + 2 * NE;   // [BT,HD]
  float* kb  = ws + 3 * NE;   // [BT,HD]
  float* vb  = ws + 4 * NE;   // [BT,HD]
  float* ab  = ws + 5 * NE;   // [BT,HD]
  float* ffa = ws + 2 * NE;   // [BT,FF] — aliases q/k/v/att (exactly 4*NE), dead by then

  embed_kernel<<<4096, 256, 0, stream>>>(x, tok, pos, h);

  const dim3 gN384(E_ / 64, BT_ / 64);    // (6,256)
  const dim3 gN1536(FF_ / 64, BT_ / 64);  // (24,256)
  const dim3 gNV((V_ + 63) / 64, BT_ / 64);

  for (int l = 0; l < L_; ++l) {
    ln_kernel<1><<<BT_ / 4, 256, 0, stream>>>(h, hn, ln1g + l * E_, ln1b + l * E_);

    gemm_f32<false, false, false><<<gN384, 256, 0, stream>>>(
        hn, Wq + (size_t)l * E_ * HD_, nullptr, nullptr, qb, BT_, HD_, E_);
    gemm_f32<false, false, false><<<gN384, 256, 0, stream>>>(
        hn, Wk + (size_t)l * E_ * HD_, nullptr, nullptr, kb, BT_, HD_, E_);
    gemm_f32<false, false, false><<<gN384, 256, 0, stream>>>(
        hn, Wv + (size_t)l * E_ * HD_, nullptr, nullptr, vb, BT_, HD_, E_);

    attn_kernel<<<B_ * H_, 256, 0, stream>>>(qb, kb, vb, ab);

    gemm_f32<true, true, false><<<gN384, 256, 0, stream>>>(
        ab, Wpr + (size_t)l * HD_ * E_, bpr + l * E_, h, h, BT_, E_, HD_);

    ln_kernel<1><<<BT_ / 4, 256, 0, stream>>>(h, hn, ln2g + l * E_, ln2b + l * E_);

    gemm_f32<true, false, true><<<gN1536, 256, 0, stream>>>(
        hn, W1 + (size_t)l * E_ * FF_, b1 + l * FF_, nullptr, ffa, BT_, FF_, E_);

    gemm_f32<true, true, false><<<gN384, 256, 0, stream>>>(
        ffa, W2 + (size_t)l * FF_ * E_, b2 + l * E_, h, h, BT_, E_, FF_);
  }

  ln_kernel<0><<<BT_ / 4, 256, 0, stream>>>(h, hn, lnfg, lnfb);

  gemm_f32<true, false, false><<<gNV, 256, 0, stream>>>(
      hn, Wlm, blm, nullptr, out, BT_, V_, E_);
}

// Round 2
// 1340.586 us; speedup vs baseline: 5.1619x; 5.1619x over previous
//
#include <hip/hip_runtime.h>

#define L_  6
#define E_  384
#define T_  256
#define H_  6
#define D_  64
#define V_  65
#define FF_ 1536
#define B_  64
#define BT_ (B_*T_)    // 16384 rows
#define HD_ 384

typedef __attribute__((ext_vector_type(8))) short short8;
typedef __attribute__((ext_vector_type(4))) float f32x4;
typedef unsigned short us;
typedef unsigned int u32;

__device__ __forceinline__ us f2bf(float f) {
  u32 u = __float_as_uint(f);
  u32 r = (u + 0x7fffu + ((u >> 16) & 1u)) >> 16;  // RNE
  return (us)r;
}

// ---------------------------------------------------------------------------
// Embedding: h[b,t,:] = tok_emb[x[b,t]] + pos_emb[t]   (fp32)
// ---------------------------------------------------------------------------
__global__ void embed_kernel(const int* __restrict__ x, const float* __restrict__ tok,
                             const float* __restrict__ pos, float* __restrict__ h) {
  const int total4 = BT_ * E_ / 4;
  for (int i = blockIdx.x * blockDim.x + threadIdx.x; i < total4;
       i += gridDim.x * blockDim.x) {
    const int flat = i << 2;
    const int row  = flat / E_;
    const int e    = flat - row * E_;
    const int id   = x[row];
    const float4 a = *reinterpret_cast<const float4*>(tok + id * E_ + e);
    const float4 p = *reinterpret_cast<const float4*>(pos + (row & (T_ - 1)) * E_ + e);
    float4 o;
    o.x = a.x + p.x; o.y = a.y + p.y; o.z = a.z + p.z; o.w = a.w + p.w;
    *reinterpret_cast<float4*>(h + flat) = o;
  }
}

// ---------------------------------------------------------------------------
// LayerNorm: fp32 in, bf16 out. One wave per row (E=384 = 64*6).
// ---------------------------------------------------------------------------
template<int DDOF>
__global__ void ln_kernel(const float* __restrict__ in, us* __restrict__ out,
                          const float* __restrict__ g, const float* __restrict__ b) {
  const int wave = threadIdx.x >> 6;
  const int lane = threadIdx.x & 63;
  const int row  = (blockIdx.x << 2) + wave;
  const float* p = in + (size_t)row * E_;
  float xv[6];
  float sum = 0.f, sq = 0.f;
#pragma unroll
  for (int i = 0; i < 6; ++i) {
    xv[i] = p[lane + (i << 6)];
    sum += xv[i];
    sq  += xv[i] * xv[i];
  }
#pragma unroll
  for (int off = 32; off > 0; off >>= 1) {
    sum += __shfl_xor(sum, off);
    sq  += __shfl_xor(sq, off);
  }
  const float mean = sum * (1.f / E_);
  const float var  = (sq - E_ * mean * mean) * (1.f / (E_ - DDOF));
  const float inv  = rsqrtf(var + 1e-5f);
  us* o = out + (size_t)row * E_;
#pragma unroll
  for (int i = 0; i < 6; ++i) {
    const int c = lane + (i << 6);
    o[c] = f2bf(g[c] * (xv[i] - mean) * inv + b[c]);
  }
}

// ---------------------------------------------------------------------------
// Weight transpose + fp32->bf16: dst[n][k] = src[k][n], zero-pad n in [N,Ndst)
// blockIdx.z = layer.
// ---------------------------------------------------------------------------
__global__ void transpose_w(const float* __restrict__ src, us* __restrict__ dst,
                            int K, int N, int Ndst, long srcLS, long dstLS) {
  __shared__ float t[32][33];
  const int n0 = blockIdx.x << 5, k0 = blockIdx.y << 5;
  const int tx = threadIdx.x & 31, ty = threadIdx.x >> 5;
  const float* s = src + (size_t)blockIdx.z * srcLS;
  us* d = dst + (size_t)blockIdx.z * dstLS;
#pragma unroll
  for (int j = 0; j < 32; j += 8) {
    const int n = n0 + tx;
    t[ty + j][tx] = (n < N) ? s[(size_t)(k0 + ty + j) * N + n] : 0.f;
  }
  __syncthreads();
#pragma unroll
  for (int j = 0; j < 32; j += 8) {
    const int n = n0 + ty + j;
    if (n < Ndst) d[(size_t)n * K + k0 + tx] = f2bf(t[tx][ty + j]);
  }
}

// ---------------------------------------------------------------------------
// Async global->LDS staging of a 128x32 bf16 tile (row-major, 64B rows),
// XOR chunk swizzle on the GLOBAL side (chunk ^= (row>>1)&3) so frag reads
// at the same XOR are bank-uniform. 2 insts/thread, 16B each.
// ---------------------------------------------------------------------------
__device__ __forceinline__ void stage_tile(const us* gbase, us* lds,
                                           int rowBase, int K, int k0, int tid) {
#pragma unroll
  for (int j = 0; j < 2; ++j) {
    const int fl  = j * 256 + tid;        // 0..511 -> 512 x 16B = 16KB? no: 8KB (2 tiles of 4KB per j)
    const int row = fl >> 2;              // 0..127
    const int c   = fl & 3;               // 16B chunk within 64B row
    const int gc  = c ^ ((row >> 1) & 3);
    const us* src = gbase + (size_t)(rowBase + row) * K + k0 + gc * 8;
    __builtin_amdgcn_global_load_lds(
        (const __attribute__((address_space(1))) u32*)src,
        (__attribute__((address_space(3))) u32*)(lds + ((fl >> 6) << 9)),
        16, 0, 0);
  }
}

// ---------------------------------------------------------------------------
// MFMA GEMM: C[M,N] = A[M,K] @ Bt[N,K]^T. Tile 128x128, BK=32, 4 waves
// (2x2), each wave 64x64 via 4x4 frags of 16x16x32_bf16.
// EPI: 0 = QKV split (q/k -> O0 [BT][768] bf16, v -> O1 transposed [B*H][64][256] bf16)
//      1 = +bias +Res -> fp32 O0 (N=384)
//      2 = +bias +ReLU -> bf16 O0
//      3 = +bias, col<65 -> fp32 O0 stride 65 (LM head)
// ---------------------------------------------------------------------------
template<int EPI>
__global__ __launch_bounds__(256)
void gemm_mfma(const us* __restrict__ A, const us* __restrict__ Bt,
               const float* __restrict__ bias, const float* Res,
               void* O0, void* O1, int M, int N, int K) {
  __shared__ us As[128 * 32];
  __shared__ us Bs[128 * 32];
  const int tid = threadIdx.x;
  const int bm = blockIdx.y << 7, bn = blockIdx.x << 7;
  const int wv = tid >> 6, ln = tid & 63;
  const int fm = ln & 15, fg = ln >> 4;
  const int wm = (wv >> 1) << 6, wn = (wv & 1) << 6;

  f32x4 acc[4][4];
  const f32x4 zz = {0.f, 0.f, 0.f, 0.f};
#pragma unroll
  for (int i = 0; i < 4; ++i)
#pragma unroll
    for (int j = 0; j < 4; ++j) acc[i][j] = zz;

  stage_tile(A, As, bm, K, 0, tid);
  stage_tile(Bt, Bs, bn, K, 0, tid);

  for (int k0 = 0;;) {
    __syncthreads();   // drains vmcnt: staged tile visible
    short8 af[4], bfr[4];
#pragma unroll
    for (int mt = 0; mt < 4; ++mt) {
      const int row = wm + mt * 16 + fm;
      af[mt] = *(const short8*)(As + row * 32 + ((fg ^ ((row >> 1) & 3)) << 3));
    }
#pragma unroll
    for (int nt = 0; nt < 4; ++nt) {
      const int row = wn + nt * 16 + fm;
      bfr[nt] = *(const short8*)(Bs + row * 32 + ((fg ^ ((row >> 1) & 3)) << 3));
    }
#pragma unroll
    for (int mt = 0; mt < 4; ++mt)
#pragma unroll
      for (int nt = 0; nt < 4; ++nt)
        acc[mt][nt] = __builtin_amdgcn_mfma_f32_16x16x32_bf16(af[mt], bfr[nt], acc[mt][nt], 0, 0, 0);
    k0 += 32;
    if (k0 >= K) break;
    __syncthreads();   // all frag reads done before overwrite
    stage_tile(A, As, bm, K, k0, tid);
    stage_tile(Bt, Bs, bn, K, k0, tid);
  }

  // ---- epilogue: lane holds rows fg*4+r, col fm of each 16x16 frag ----
#pragma unroll
  for (int mt = 0; mt < 4; ++mt) {
#pragma unroll
    for (int nt = 0; nt < 4; ++nt) {
      const int col  = bn + wn + nt * 16 + fm;
      const int row0 = bm + wm + mt * 16 + fg * 4;
      if (EPI == 0) {
        if (col < 768) {                      // q or k region
          us* qk = (us*)O0;
#pragma unroll
          for (int r = 0; r < 4; ++r)
            qk[(size_t)(row0 + r) * 768 + col] = f2bf(acc[mt][nt][r]);
        } else {                              // v -> transposed [B*H][64][256]
          const int d = col - 768;
          const int hh = d >> 6, dd = d & 63;
          const int bI = row0 >> 8, t0 = row0 & 255;
          us* vt = (us*)O1;
          ushort4 pk;
          pk.x = f2bf(acc[mt][nt][0]); pk.y = f2bf(acc[mt][nt][1]);
          pk.z = f2bf(acc[mt][nt][2]); pk.w = f2bf(acc[mt][nt][3]);
          *reinterpret_cast<ushort4*>(vt + ((size_t)((bI * H_ + hh) * 64 + dd)) * 256 + t0) = pk;
        }
      } else if (EPI == 1) {
        float* o = (float*)O0;
        const float bc = bias[col];
#pragma unroll
        for (int r = 0; r < 4; ++r) {
          const size_t idx = (size_t)(row0 + r) * N + col;
          o[idx] = acc[mt][nt][r] + bc + Res[idx];
        }
      } else if (EPI == 2) {
        us* o = (us*)O0;
        const float bc = bias[col];
#pragma unroll
        for (int r = 0; r < 4; ++r)
          o[(size_t)(row0 + r) * N + col] = f2bf(fmaxf(acc[mt][nt][r] + bc, 0.f));
      } else {
        if (col < V_) {
          float* o = (float*)O0;
          const float bc = bias[col];
#pragma unroll
          for (int r = 0; r < 4; ++r)
            o[(size_t)(row0 + r) * V_ + col] = acc[mt][nt][r] + bc;
        }
      }
    }
  }
}

// ---------------------------------------------------------------------------
// MFMA flash attention. Block = (b, h, 64-query tile); 4 waves x 16 queries.
// qk: [BT][768] bf16 (q cols 0-383, k cols 384-767, head h at h*64).
// vT: [B*H][64][256] bf16 (dim-major). ab out: [BT][384] bf16.
// ---------------------------------------------------------------------------
__global__ __launch_bounds__(256)
void attn_mfma(const us* __restrict__ qk, const us* __restrict__ vT,
               us* __restrict__ ab) {
  __shared__ us Plds[4][16 * 72];   // per-wave P tile, stride 72 (pad)
  const int tid = threadIdx.x, w = tid >> 6, l = tid & 63;
  const int m = l & 15, g = l >> 4;
  const int bi = blockIdx.x;
  const int b = bi / 24, rem = bi - b * 24, h = rem >> 2, qt = rem & 3;
  const int qrow = (b << 8) + (qt << 6) + (w << 4);

  short8 qf0, qf1;
  {
    const us* qp = qk + (size_t)(qrow + m) * 768 + h * 64 + g * 8;
    qf0 = *(const short8*)qp;
    qf1 = *(const short8*)(qp + 32);
  }
  float mrow[4], ssum[4];
  f32x4 o[4];
  const f32x4 zz = {0.f, 0.f, 0.f, 0.f};
#pragma unroll
  for (int r = 0; r < 4; ++r) { mrow[r] = -1e30f; ssum[r] = 0.f; o[r] = zz; }

  for (int kt = 0; kt <= qt; ++kt) {
    // ---- S = Q K^T (16 queries x 64 keys) ----
    f32x4 s[4];
#pragma unroll
    for (int nt = 0; nt < 4; ++nt) {
      const us* kp = qk + (size_t)((b << 8) + (kt << 6) + nt * 16 + m) * 768 + 384 + h * 64 + g * 8;
      short8 kf0 = *(const short8*)kp;
      short8 kf1 = *(const short8*)(kp + 32);
      f32x4 z = zz;
      z = __builtin_amdgcn_mfma_f32_16x16x32_bf16(qf0, kf0, z, 0, 0, 0);
      z = __builtin_amdgcn_mfma_f32_16x16x32_bf16(qf1, kf1, z, 0, 0, 0);
      s[nt] = z;
    }
    // ---- mask + online softmax ----
    const bool diag = (kt == qt);
    float p[4][4], tmax[4];
#pragma unroll
    for (int r = 0; r < 4; ++r) tmax[r] = -1e30f;
#pragma unroll
    for (int nt = 0; nt < 4; ++nt)
#pragma unroll
      for (int r = 0; r < 4; ++r) {
        float v = s[nt][r] * 0.125f;
        if (diag) {
          const int key = nt * 16 + m;
          const int qq  = (w << 4) + (g << 2) + r;
          if (key > qq) v = -1e30f;
        }
        p[nt][r] = v;
        tmax[r] = fmaxf(tmax[r], v);
      }
#pragma unroll
    for (int xm = 1; xm < 16; xm <<= 1)
#pragma unroll
      for (int r = 0; r < 4; ++r) tmax[r] = fmaxf(tmax[r], __shfl_xor(tmax[r], xm));
    float sc[4], tsum[4];
#pragma unroll
    for (int r = 0; r < 4; ++r) {
      const float nm = fmaxf(mrow[r], tmax[r]);
      sc[r] = __expf(mrow[r] - nm);
      mrow[r] = nm;
      tsum[r] = 0.f;
    }
#pragma unroll
    for (int nt = 0; nt < 4; ++nt)
#pragma unroll
      for (int r = 0; r < 4; ++r) {
        p[nt][r] = __expf(p[nt][r] - mrow[r]);
        tsum[r] += p[nt][r];
      }
#pragma unroll
    for (int xm = 1; xm < 16; xm <<= 1)
#pragma unroll
      for (int r = 0; r < 4; ++r) tsum[r] += __shfl_xor(tsum[r], xm);
#pragma unroll
    for (int r = 0; r < 4; ++r) ssum[r] = ssum[r] * sc[r] + tsum[r];
#pragma unroll
    for (int nt = 0; nt < 4; ++nt)
#pragma unroll
      for (int r = 0; r < 4; ++r) o[nt][r] *= sc[r];
    // ---- P -> LDS (bf16, C-layout -> A-layout transpose via LDS) ----
#pragma unroll
    for (int nt = 0; nt < 4; ++nt)
#pragma unroll
      for (int r = 0; r < 4; ++r)
        Plds[w][(g * 4 + r) * 72 + nt * 16 + m] = f2bf(p[nt][r]);
    // ---- O += P V ----
#pragma unroll
    for (int kc = 0; kc < 2; ++kc) {
      short8 pa = *(const short8*)&Plds[w][m * 72 + kc * 32 + g * 8];
#pragma unroll
      for (int nd = 0; nd < 4; ++nd) {
        const us* vp = vT + (size_t)((b * H_ + h) * 64 + nd * 16 + m) * 256 + (kt << 6) + kc * 32 + g * 8;
        short8 vf = *(const short8*)vp;
        o[nd] = __builtin_amdgcn_mfma_f32_16x16x32_bf16(pa, vf, o[nd], 0, 0, 0);
      }
    }
  }
  // ---- normalize + write ----
#pragma unroll
  for (int r = 0; r < 4; ++r) {
    const float inv = 1.f / ssum[r];
    const size_t rowoff = (size_t)(qrow + g * 4 + r) * 384 + h * 64;
#pragma unroll
    for (int nd = 0; nd < 4; ++nd)
      ab[rowoff + nd * 16 + m] = f2bf(o[nd][r] * inv);
  }
}

// ---------------------------------------------------------------------------
extern "C" void kernel_launch(void* const* d_in, const int* in_sizes, int n_in,
                              void* d_out, int out_size, void* d_ws, size_t ws_size,
                              hipStream_t stream) {
  const int*   x    = (const int*)  d_in[0];
  const float* tok  = (const float*)d_in[1];
  const float* pos  = (const float*)d_in[2];
  const float* Wq   = (const float*)d_in[3];
  const float* Wk   = (const float*)d_in[4];
  const float* Wv   = (const float*)d_in[5];
  const float* Wpr  = (const float*)d_in[6];
  const float* bpr  = (const float*)d_in[7];
  const float* W1   = (const float*)d_in[8];
  const float* b1   = (const float*)d_in[9];
  const float* W2   = (const float*)d_in[10];
  const float* b2   = (const float*)d_in[11];
  const float* ln1g = (const float*)d_in[12];
  const float* ln1b = (const float*)d_in[13];
  const float* ln2g = (const float*)d_in[14];
  const float* ln2b = (const float*)d_in[15];
  const float* lnfg = (const float*)d_in[16];
  const float* lnfb = (const float*)d_in[17];
  const float* Wlm  = (const float*)d_in[18];
  const float* blm  = (const float*)d_in[19];
  float* out = (float*)d_out;

  char* W = (char*)d_ws;
  float* h    = (float*)(W + 0);               // [BT][384] fp32        25.2 MB
  us*    hn   = (us*)(W + 25165824);           // [BT][384] bf16        12.6 MB
  us*    qkb  = (us*)(W + 37748736);           // [BT][768] bf16        25.2 MB
  us*    vTb  = (us*)(W + 62914560);           // [B*H][64][256] bf16   12.6 MB
  us*    abb  = (us*)(W + 75497472);           // [BT][384] bf16        12.6 MB
  us*    ffa  = (us*)(W + 37748736);           // [BT][1536] bf16 (aliases qk+vT+ab)
  us*    qkvT = (us*)(W + 88080384);           // [L][1152][384] bf16
  us*    projT= (us*)(W + 93388800);           // [L][384][384]
  us*    W1T  = (us*)(W + 95158272);           // [L][1536][384]
  us*    W2T  = (us*)(W + 102236160);          // [L][384][1536]
  us*    WlmT = (us*)(W + 109314048);          // [128][384] (rows 65+ zero)

  // ---- one-time weight conversion (runs every call; ~40 us) ----
  transpose_w<<<dim3(12,12,6), 256, 0, stream>>>(Wq,  qkvT,           384, 384, 384, 147456, 442368);
  transpose_w<<<dim3(12,12,6), 256, 0, stream>>>(Wk,  qkvT + 147456,  384, 384, 384, 147456, 442368);
  transpose_w<<<dim3(12,12,6), 256, 0, stream>>>(Wv,  qkvT + 294912,  384, 384, 384, 147456, 442368);
  transpose_w<<<dim3(12,12,6), 256, 0, stream>>>(Wpr, projT,          384, 384, 384, 147456, 147456);
  transpose_w<<<dim3(48,12,6), 256, 0, stream>>>(W1,  W1T,            384, 1536, 1536, 589824, 589824);
  transpose_w<<<dim3(12,48,6), 256, 0, stream>>>(W2,  W2T,            1536, 384, 384, 589824, 589824);
  transpose_w<<<dim3(4,12,1),  256, 0, stream>>>(Wlm, WlmT,           384, 65, 128, 0, 0);

  embed_kernel<<<2048, 256, 0, stream>>>(x, tok, pos, h);

  for (int l = 0; l < L_; ++l) {
    ln_kernel<1><<<BT_/4, 256, 0, stream>>>(h, hn, ln1g + l*E_, ln1b + l*E_);
    gemm_mfma<0><<<dim3(9,128), 256, 0, stream>>>(
        hn, qkvT + (size_t)l*442368, nullptr, nullptr, qkb, vTb, BT_, 1152, 384);
    attn_mfma<<<B_*H_*4, 256, 0, stream>>>(qkb, vTb, abb);
    gemm_mfma<1><<<dim3(3,128), 256, 0, stream>>>(
        abb, projT + (size_t)l*147456, bpr + l*E_, h, h, nullptr, BT_, 384, 384);
    ln_kernel<1><<<BT_/4, 256, 0, stream>>>(h, hn, ln2g + l*E_, ln2b + l*E_);
    gemm_mfma<2><<<dim3(12,128), 256, 0, stream>>>(
        hn, W1T + (size_t)l*589824, b1 + l*FF_, nullptr, ffa, nullptr, BT_, 1536, 384);
    gemm_mfma<1><<<dim3(3,128), 256, 0, stream>>>(
        ffa, W2T + (size_t)l*589824, b2 + l*E_, h, h, nullptr, BT_, 384, 1536);
  }

  ln_kernel<0><<<BT_/4, 256, 0, stream>>>(h, hn, lnfg, lnfb);
  gemm_mfma<3><<<dim3(1,128), 256, 0, stream>>>(
      hn, WlmT, blm, nullptr, out, nullptr, BT_, 128, 384);
}

// Round 3
// 1150.677 us; speedup vs baseline: 6.0138x; 1.1650x over previous
//
#include <hip/hip_runtime.h>

#define L_  6
#define E_  384
#define T_  256
#define H_  6
#define D_  64
#define V_  65
#define FF_ 1536
#define B_  64
#define BT_ (B_*T_)    // 16384 rows
#define HD_ 384

typedef __attribute__((ext_vector_type(8))) short short8;
typedef __attribute__((ext_vector_type(4))) float f32x4;
typedef unsigned short us;
typedef unsigned int u32;

__device__ __forceinline__ us f2bf(float f) {
  u32 u = __float_as_uint(f);
  u32 r = (u + 0x7fffu + ((u >> 16) & 1u)) >> 16;  // RNE
  return (us)r;
}

// XCD-chunked bijective block remap (requires gridDim.x % 8 == 0).
__device__ __forceinline__ int xcd_swz(int b, int nwg) {
  const int q = nwg >> 3;
  return (b & 7) * q + (b >> 3);
}

// ---------------------------------------------------------------------------
// Embedding: h[b,t,:] = tok_emb[x[b,t]] + pos_emb[t]   (fp32)
// ---------------------------------------------------------------------------
__global__ void embed_kernel(const int* __restrict__ x, const float* __restrict__ tok,
                             const float* __restrict__ pos, float* __restrict__ h) {
  const int total4 = BT_ * E_ / 4;
  for (int i = blockIdx.x * blockDim.x + threadIdx.x; i < total4;
       i += gridDim.x * blockDim.x) {
    const int flat = i << 2;
    const int row  = flat / E_;
    const int e    = flat - row * E_;
    const int id   = x[row];
    const float4 a = *reinterpret_cast<const float4*>(tok + id * E_ + e);
    const float4 p = *reinterpret_cast<const float4*>(pos + (row & (T_ - 1)) * E_ + e);
    float4 o;
    o.x = a.x + p.x; o.y = a.y + p.y; o.z = a.z + p.z; o.w = a.w + p.w;
    *reinterpret_cast<float4*>(h + flat) = o;
  }
}

// ---------------------------------------------------------------------------
// LayerNorm: fp32 in, bf16 out. One wave per row (E=384 = 64*6).
// ---------------------------------------------------------------------------
template<int DDOF>
__global__ void ln_kernel(const float* __restrict__ in, us* __restrict__ out,
                          const float* __restrict__ g, const float* __restrict__ b) {
  const int wave = threadIdx.x >> 6;
  const int lane = threadIdx.x & 63;
  const int row  = (blockIdx.x << 2) + wave;
  const float* p = in + (size_t)row * E_;
  float xv[6];
  float sum = 0.f, sq = 0.f;
#pragma unroll
  for (int i = 0; i < 6; ++i) {
    xv[i] = p[lane + (i << 6)];
    sum += xv[i];
    sq  += xv[i] * xv[i];
  }
#pragma unroll
  for (int off = 32; off > 0; off >>= 1) {
    sum += __shfl_xor(sum, off);
    sq  += __shfl_xor(sq, off);
  }
  const float mean = sum * (1.f / E_);
  const float var  = (sq - E_ * mean * mean) * (1.f / (E_ - DDOF));
  const float inv  = rsqrtf(var + 1e-5f);
  us* o = out + (size_t)row * E_;
#pragma unroll
  for (int i = 0; i < 6; ++i) {
    const int c = lane + (i << 6);
    o[c] = f2bf(g[c] * (xv[i] - mean) * inv + b[c]);
  }
}

// ---------------------------------------------------------------------------
// Weight transpose + fp32->bf16: dst[n][k] = src[k][n], zero-pad n in [N,Ndst)
// ---------------------------------------------------------------------------
__global__ void transpose_w(const float* __restrict__ src, us* __restrict__ dst,
                            int K, int N, int Ndst, long srcLS, long dstLS) {
  __shared__ float t[32][33];
  const int n0 = blockIdx.x << 5, k0 = blockIdx.y << 5;
  const int tx = threadIdx.x & 31, ty = threadIdx.x >> 5;
  const float* s = src + (size_t)blockIdx.z * srcLS;
  us* d = dst + (size_t)blockIdx.z * dstLS;
#pragma unroll
  for (int j = 0; j < 32; j += 8) {
    const int n = n0 + tx;
    t[ty + j][tx] = (n < N) ? s[(size_t)(k0 + ty + j) * N + n] : 0.f;
  }
  __syncthreads();
#pragma unroll
  for (int j = 0; j < 32; j += 8) {
    const int n = n0 + ty + j;
    if (n < Ndst) d[(size_t)n * K + k0 + tx] = f2bf(t[tx][ty + j]);
  }
}

// ---------------------------------------------------------------------------
// Async global->LDS staging of a ROWSx32 bf16 tile (row-major 64B rows),
// XOR chunk swizzle applied on the GLOBAL source side.
// ---------------------------------------------------------------------------
template<int ROWS>
__device__ __forceinline__ void stage_tile(const us* gbase, us* lds,
                                           int rowBase, int K, int k0, int tid) {
#pragma unroll
  for (int j = 0; j < ROWS / 64; ++j) {
    const int fl  = j * 256 + tid;
    const int row = fl >> 2;              // 0..ROWS-1
    const int c   = fl & 3;               // 16B chunk within 64B row
    const int gc  = c ^ ((row >> 1) & 3);
    const us* src = gbase + (size_t)(rowBase + row) * K + k0 + gc * 8;
    __builtin_amdgcn_global_load_lds(
        (const __attribute__((address_space(1))) u32*)src,
        (__attribute__((address_space(3))) u32*)(lds + ((fl >> 6) << 9)),
        16, 0, 0);
  }
}

// ---------------------------------------------------------------------------
// MFMA GEMM: C = A[M,K] @ Bt[N,K]^T. Tile (FM*32)x(FN*32), BK=32, 4 waves
// (2x2), per-wave FMxFN frags of 16x16x32_bf16. Double-buffered 2-phase
// K-loop: stage next tile, compute current, one __syncthreads per step.
// 1D grid (nwg = (N/BN)*(M/BM), % 8 == 0), XCD-chunked remap, bn fastest.
// EPI: 0 = QKV split (q/k -> O0 [BT][768] bf16, v -> O1 [B*H][64][256] bf16)
//      1 = +bias +Res(fp32) -> fp32 O0
//      2 = +bias +ReLU -> bf16 O0
//      3 = +bias, col<65 -> fp32 O0 stride 65 (LM head)
// ---------------------------------------------------------------------------
template<int FM, int FN, int EPI>
__global__ __launch_bounds__(256)
void gemm_mfma(const us* __restrict__ A, const us* __restrict__ Bt,
               const float* __restrict__ bias, const float* Res,
               void* O0, void* O1, int N, int K, int gx) {
  constexpr int BM = FM * 32, BN = FN * 32;
  __shared__ us As[2][BM * 32];
  __shared__ us Bs[2][BN * 32];
  const int tid = threadIdx.x;
  const int lid = xcd_swz(blockIdx.x, gridDim.x);
  const int bnI = lid % gx, bmI = lid / gx;
  const int bm = bmI * BM, bn = bnI * BN;
  const int wv = tid >> 6, ln = tid & 63;
  const int fm = ln & 15, fg = ln >> 4;
  const int wm = (wv >> 1) * (FM * 16), wn = (wv & 1) * (FN * 16);

  f32x4 acc[FM][FN];
  const f32x4 zz = {0.f, 0.f, 0.f, 0.f};
#pragma unroll
  for (int i = 0; i < FM; ++i)
#pragma unroll
    for (int j = 0; j < FN; ++j) acc[i][j] = zz;

  stage_tile<BM>(A, As[0], bm, K, 0, tid);
  stage_tile<BN>(Bt, Bs[0], bn, K, 0, tid);
  __syncthreads();

  const int NT = K >> 5;
  int cur = 0;
  for (int t = 0; t < NT; ++t) {
    if (t + 1 < NT) {
      stage_tile<BM>(A, As[cur ^ 1], bm, K, (t + 1) << 5, tid);
      stage_tile<BN>(Bt, Bs[cur ^ 1], bn, K, (t + 1) << 5, tid);
    }
    short8 af[FM], bfr[FN];
#pragma unroll
    for (int mt = 0; mt < FM; ++mt) {
      const int row = wm + mt * 16 + fm;
      af[mt] = *(const short8*)(As[cur] + row * 32 + ((fg ^ ((row >> 1) & 3)) << 3));
    }
#pragma unroll
    for (int nt = 0; nt < FN; ++nt) {
      const int row = wn + nt * 16 + fm;
      bfr[nt] = *(const short8*)(Bs[cur] + row * 32 + ((fg ^ ((row >> 1) & 3)) << 3));
    }
#pragma unroll
    for (int mt = 0; mt < FM; ++mt)
#pragma unroll
      for (int nt = 0; nt < FN; ++nt)
        acc[mt][nt] = __builtin_amdgcn_mfma_f32_16x16x32_bf16(af[mt], bfr[nt], acc[mt][nt], 0, 0, 0);
    __syncthreads();   // staged next-tile arrived; all reads of cur done
    cur ^= 1;
  }

  // ---- epilogue: lane holds rows fg*4+r, col fm of each 16x16 frag ----
#pragma unroll
  for (int mt = 0; mt < FM; ++mt) {
#pragma unroll
    for (int nt = 0; nt < FN; ++nt) {
      const int col  = bn + wn + nt * 16 + fm;
      const int row0 = bm + wm + mt * 16 + fg * 4;
      if (EPI == 0) {
        if (col < 768) {                      // q or k region
          us* qk = (us*)O0;
#pragma unroll
          for (int r = 0; r < 4; ++r)
            qk[(size_t)(row0 + r) * 768 + col] = f2bf(acc[mt][nt][r]);
        } else {                              // v -> transposed [B*H][64][256]
          const int d = col - 768;
          const int hh = d >> 6, dd = d & 63;
          const int bI = row0 >> 8, t0 = row0 & 255;
          us* vt = (us*)O1;
          ushort4 pk;
          pk.x = f2bf(acc[mt][nt][0]); pk.y = f2bf(acc[mt][nt][1]);
          pk.z = f2bf(acc[mt][nt][2]); pk.w = f2bf(acc[mt][nt][3]);
          *reinterpret_cast<ushort4*>(vt + ((size_t)((bI * H_ + hh) * 64 + dd)) * 256 + t0) = pk;
        }
      } else if (EPI == 1) {
        float* o = (float*)O0;
        const float bc = bias[col];
#pragma unroll
        for (int r = 0; r < 4; ++r) {
          const size_t idx = (size_t)(row0 + r) * N + col;
          o[idx] = acc[mt][nt][r] + bc + Res[idx];
        }
      } else if (EPI == 2) {
        us* o = (us*)O0;
        const float bc = bias[col];
#pragma unroll
        for (int r = 0; r < 4; ++r)
          o[(size_t)(row0 + r) * N + col] = f2bf(fmaxf(acc[mt][nt][r] + bc, 0.f));
      } else {
        if (col < V_) {
          float* o = (float*)O0;
          const float bc = bias[col];
#pragma unroll
          for (int r = 0; r < 4; ++r)
            o[(size_t)(row0 + r) * V_ + col] = acc[mt][nt][r] + bc;
        }
      }
    }
  }
}

// ---------------------------------------------------------------------------
// MFMA flash attention. Block = (b, h, 64-query tile); 4 waves x 16 queries.
// qk: [BT][768] bf16 (q cols 0-383, k cols 384-767, head h at h*64).
// vT: [B*H][64][256] bf16 (dim-major). ab out: [BT][384] bf16.
// ---------------------------------------------------------------------------
__global__ __launch_bounds__(256)
void attn_mfma(const us* __restrict__ qk, const us* __restrict__ vT,
               us* __restrict__ ab) {
  __shared__ us Plds[4][16 * 72];   // per-wave P tile, stride 72 (pad)
  const int tid = threadIdx.x, w = tid >> 6, l = tid & 63;
  const int m = l & 15, g = l >> 4;
  const int bi = xcd_swz(blockIdx.x, gridDim.x);
  const int b = bi / 24, rem = bi - b * 24, h = rem >> 2, qt = rem & 3;
  const int qrow = (b << 8) + (qt << 6) + (w << 4);

  short8 qf0, qf1;
  {
    const us* qp = qk + (size_t)(qrow + m) * 768 + h * 64 + g * 8;
    qf0 = *(const short8*)qp;
    qf1 = *(const short8*)(qp + 32);
  }
  float mrow[4], ssum[4];
  f32x4 o[4];
  const f32x4 zz = {0.f, 0.f, 0.f, 0.f};
#pragma unroll
  for (int r = 0; r < 4; ++r) { mrow[r] = -1e30f; ssum[r] = 0.f; o[r] = zz; }

  for (int kt = 0; kt <= qt; ++kt) {
    // ---- S = Q K^T (16 queries x 64 keys) ----
    f32x4 s[4];
#pragma unroll
    for (int nt = 0; nt < 4; ++nt) {
      const us* kp = qk + (size_t)((b << 8) + (kt << 6) + nt * 16 + m) * 768 + 384 + h * 64 + g * 8;
      short8 kf0 = *(const short8*)kp;
      short8 kf1 = *(const short8*)(kp + 32);
      f32x4 z = zz;
      z = __builtin_amdgcn_mfma_f32_16x16x32_bf16(qf0, kf0, z, 0, 0, 0);
      z = __builtin_amdgcn_mfma_f32_16x16x32_bf16(qf1, kf1, z, 0, 0, 0);
      s[nt] = z;
    }
    // ---- mask + online softmax ----
    const bool diag = (kt == qt);
    float p[4][4], tmax[4];
#pragma unroll
    for (int r = 0; r < 4; ++r) tmax[r] = -1e30f;
#pragma unroll
    for (int nt = 0; nt < 4; ++nt)
#pragma unroll
      for (int r = 0; r < 4; ++r) {
        float v = s[nt][r] * 0.125f;
        if (diag) {
          const int key = nt * 16 + m;
          const int qq  = (w << 4) + (g << 2) + r;
          if (key > qq) v = -1e30f;
        }
        p[nt][r] = v;
        tmax[r] = fmaxf(tmax[r], v);
      }
#pragma unroll
    for (int xm = 1; xm < 16; xm <<= 1)
#pragma unroll
      for (int r = 0; r < 4; ++r) tmax[r] = fmaxf(tmax[r], __shfl_xor(tmax[r], xm));
    float sc[4], tsum[4];
#pragma unroll
    for (int r = 0; r < 4; ++r) {
      const float nm = fmaxf(mrow[r], tmax[r]);
      sc[r] = __expf(mrow[r] - nm);
      mrow[r] = nm;
      tsum[r] = 0.f;
    }
#pragma unroll
    for (int nt = 0; nt < 4; ++nt)
#pragma unroll
      for (int r = 0; r < 4; ++r) {
        p[nt][r] = __expf(p[nt][r] - mrow[r]);
        tsum[r] += p[nt][r];
      }
#pragma unroll
    for (int xm = 1; xm < 16; xm <<= 1)
#pragma unroll
      for (int r = 0; r < 4; ++r) tsum[r] += __shfl_xor(tsum[r], xm);
#pragma unroll
    for (int r = 0; r < 4; ++r) ssum[r] = ssum[r] * sc[r] + tsum[r];
#pragma unroll
    for (int nt = 0; nt < 4; ++nt)
#pragma unroll
      for (int r = 0; r < 4; ++r) o[nt][r] *= sc[r];
    // ---- P -> LDS (bf16, C-layout -> A-layout transpose via LDS) ----
#pragma unroll
    for (int nt = 0; nt < 4; ++nt)
#pragma unroll
      for (int r = 0; r < 4; ++r)
        Plds[w][(g * 4 + r) * 72 + nt * 16 + m] = f2bf(p[nt][r]);
    // ---- O += P V ----
#pragma unroll
    for (int kc = 0; kc < 2; ++kc) {
      short8 pa = *(const short8*)&Plds[w][m * 72 + kc * 32 + g * 8];
#pragma unroll
      for (int nd = 0; nd < 4; ++nd) {
        const us* vp = vT + (size_t)((b * H_ + h) * 64 + nd * 16 + m) * 256 + (kt << 6) + kc * 32 + g * 8;
        short8 vf = *(const short8*)vp;
        o[nd] = __builtin_amdgcn_mfma_f32_16x16x32_bf16(pa, vf, o[nd], 0, 0, 0);
      }
    }
  }
  // ---- normalize + write ----
#pragma unroll
  for (int r = 0; r < 4; ++r) {
    const float inv = 1.f / ssum[r];
    const size_t rowoff = (size_t)(qrow + g * 4 + r) * 384 + h * 64;
#pragma unroll
    for (int nd = 0; nd < 4; ++nd)
      ab[rowoff + nd * 16 + m] = f2bf(o[nd][r] * inv);
  }
}

// ---------------------------------------------------------------------------
extern "C" void kernel_launch(void* const* d_in, const int* in_sizes, int n_in,
                              void* d_out, int out_size, void* d_ws, size_t ws_size,
                              hipStream_t stream) {
  const int*   x    = (const int*)  d_in[0];
  const float* tok  = (const float*)d_in[1];
  const float* pos  = (const float*)d_in[2];
  const float* Wq   = (const float*)d_in[3];
  const float* Wk   = (const float*)d_in[4];
  const float* Wv   = (const float*)d_in[5];
  const float* Wpr  = (const float*)d_in[6];
  const float* bpr  = (const float*)d_in[7];
  const float* W1   = (const float*)d_in[8];
  const float* b1   = (const float*)d_in[9];
  const float* W2   = (const float*)d_in[10];
  const float* b2   = (const float*)d_in[11];
  const float* ln1g = (const float*)d_in[12];
  const float* ln1b = (const float*)d_in[13];
  const float* ln2g = (const float*)d_in[14];
  const float* ln2b = (const float*)d_in[15];
  const float* lnfg = (const float*)d_in[16];
  const float* lnfb = (const float*)d_in[17];
  const float* Wlm  = (const float*)d_in[18];
  const float* blm  = (const float*)d_in[19];
  float* out = (float*)d_out;

  char* W = (char*)d_ws;
  float* h    = (float*)(W + 0);               // [BT][384] fp32        25.2 MB
  us*    hn   = (us*)(W + 25165824);           // [BT][384] bf16        12.6 MB
  us*    qkb  = (us*)(W + 37748736);           // [BT][768] bf16        25.2 MB
  us*    vTb  = (us*)(W + 62914560);           // [B*H][64][256] bf16   12.6 MB
  us*    abb  = (us*)(W + 75497472);           // [BT][384] bf16        12.6 MB
  us*    ffa  = (us*)(W + 37748736);           // [BT][1536] bf16 (aliases qk+vT+ab)
  us*    qkvT = (us*)(W + 88080384);           // [L][1152][384] bf16
  us*    projT= (us*)(W + 93388800);           // [L][384][384]
  us*    W1T  = (us*)(W + 95158272);           // [L][1536][384]
  us*    W2T  = (us*)(W + 102236160);          // [L][384][1536]
  us*    WlmT = (us*)(W + 109314048);          // [128][384] (rows 65+ zero)

  // ---- weight conversion ----
  transpose_w<<<dim3(12,12,6), 256, 0, stream>>>(Wq,  qkvT,           384, 384, 384, 147456, 442368);
  transpose_w<<<dim3(12,12,6), 256, 0, stream>>>(Wk,  qkvT + 147456,  384, 384, 384, 147456, 442368);
  transpose_w<<<dim3(12,12,6), 256, 0, stream>>>(Wv,  qkvT + 294912,  384, 384, 384, 147456, 442368);
  transpose_w<<<dim3(12,12,6), 256, 0, stream>>>(Wpr, projT,          384, 384, 384, 147456, 147456);
  transpose_w<<<dim3(48,12,6), 256, 0, stream>>>(W1,  W1T,            384, 1536, 1536, 589824, 589824);
  transpose_w<<<dim3(12,48,6), 256, 0, stream>>>(W2,  W2T,            1536, 384, 384, 589824, 589824);
  transpose_w<<<dim3(4,12,1),  256, 0, stream>>>(Wlm, WlmT,           384, 65, 128, 0, 0);

  embed_kernel<<<2048, 256, 0, stream>>>(x, tok, pos, h);

  for (int l = 0; l < L_; ++l) {
    ln_kernel<1><<<BT_/4, 256, 0, stream>>>(h, hn, ln1g + l*E_, ln1b + l*E_);
    // QKV: N=1152, 128x128 tiles -> 9*128 = 1152 blocks
    gemm_mfma<4,4,0><<<1152, 256, 0, stream>>>(
        hn, qkvT + (size_t)l*442368, nullptr, nullptr, qkb, vTb, 1152, 384, 9);
    attn_mfma<<<B_*H_*4, 256, 0, stream>>>(qkb, vTb, abb);
    // proj: N=384, 64x128 tiles -> 3*256 = 768 blocks
    gemm_mfma<2,4,1><<<768, 256, 0, stream>>>(
        abb, projT + (size_t)l*147456, bpr + l*E_, h, h, nullptr, 384, 384, 3);
    ln_kernel<1><<<BT_/4, 256, 0, stream>>>(h, hn, ln2g + l*E_, ln2b + l*E_);
    // FF1: N=1536, 128x128 tiles -> 12*128 = 1536 blocks
    gemm_mfma<4,4,2><<<1536, 256, 0, stream>>>(
        hn, W1T + (size_t)l*589824, b1 + l*FF_, nullptr, ffa, nullptr, 1536, 384, 12);
    // FF2: N=384, K=1536, 64x128 tiles -> 768 blocks
    gemm_mfma<2,4,1><<<768, 256, 0, stream>>>(
        ffa, W2T + (size_t)l*589824, b2 + l*E_, h, h, nullptr, 384, 1536, 3);
  }

  ln_kernel<0><<<BT_/4, 256, 0, stream>>>(h, hn, lnfg, lnfb);
  // LM head: N=128(padded), 64x128 tiles -> 1*256 = 256 blocks
  gemm_mfma<2,4,3><<<256, 256, 0, stream>>>(
      hn, WlmT, blm, nullptr, out, nullptr, 128, 384, 1);
}

// Round 4
// 1027.837 us; speedup vs baseline: 6.7325x; 1.1195x over previous
//
#include <hip/hip_runtime.h>

#define L_  6
#define E_  384
#define T_  256
#define H_  6
#define D_  64
#define V_  65
#define FF_ 1536
#define B_  64
#define BT_ (B_*T_)    // 16384 rows
#define HD_ 384

typedef __attribute__((ext_vector_type(8))) short short8;
typedef __attribute__((ext_vector_type(4))) float f32x4;
typedef unsigned short us;
typedef unsigned int u32;

__device__ __forceinline__ us f2bf(float f) {
  u32 u = __float_as_uint(f);
  u32 r = (u + 0x7fffu + ((u >> 16) & 1u)) >> 16;  // RNE
  return (us)r;
}

// XCD-chunked bijective block remap (requires gridDim.x % 8 == 0).
__device__ __forceinline__ int xcd_swz(int b, int nwg) {
  const int q = nwg >> 3;
  return (b & 7) * q + (b >> 3);
}

// ---------------------------------------------------------------------------
// Embedding: h[b,t,:] = tok_emb[x[b,t]] + pos_emb[t]   (fp32)
// ---------------------------------------------------------------------------
__global__ void embed_kernel(const int* __restrict__ x, const float* __restrict__ tok,
                             const float* __restrict__ pos, float* __restrict__ h) {
  const int total4 = BT_ * E_ / 4;
  for (int i = blockIdx.x * blockDim.x + threadIdx.x; i < total4;
       i += gridDim.x * blockDim.x) {
    const int flat = i << 2;
    const int row  = flat / E_;
    const int e    = flat - row * E_;
    const int id   = x[row];
    const float4 a = *reinterpret_cast<const float4*>(tok + id * E_ + e);
    const float4 p = *reinterpret_cast<const float4*>(pos + (row & (T_ - 1)) * E_ + e);
    float4 o;
    o.x = a.x + p.x; o.y = a.y + p.y; o.z = a.z + p.z; o.w = a.w + p.w;
    *reinterpret_cast<float4*>(h + flat) = o;
  }
}

// ---------------------------------------------------------------------------
// LayerNorm: fp32 in, bf16 out. One wave per row (E=384 = 64*6).
// ---------------------------------------------------------------------------
template<int DDOF>
__global__ void ln_kernel(const float* __restrict__ in, us* __restrict__ out,
                          const float* __restrict__ g, const float* __restrict__ b) {
  const int wave = threadIdx.x >> 6;
  const int lane = threadIdx.x & 63;
  const int row  = (blockIdx.x << 2) + wave;
  const float* p = in + (size_t)row * E_;
  float xv[6];
  float sum = 0.f, sq = 0.f;
#pragma unroll
  for (int i = 0; i < 6; ++i) {
    xv[i] = p[lane + (i << 6)];
    sum += xv[i];
    sq  += xv[i] * xv[i];
  }
#pragma unroll
  for (int off = 32; off > 0; off >>= 1) {
    sum += __shfl_xor(sum, off);
    sq  += __shfl_xor(sq, off);
  }
  const float mean = sum * (1.f / E_);
  const float var  = (sq - E_ * mean * mean) * (1.f / (E_ - DDOF));
  const float inv  = rsqrtf(var + 1e-5f);
  us* o = out + (size_t)row * E_;
#pragma unroll
  for (int i = 0; i < 6; ++i) {
    const int c = lane + (i << 6);
    o[c] = f2bf(g[c] * (xv[i] - mean) * inv + b[c]);
  }
}

// ---------------------------------------------------------------------------
// Weight transpose + fp32->bf16: dst[n][k] = src[k][n], zero-pad n in [N,Ndst)
// ---------------------------------------------------------------------------
__global__ void transpose_w(const float* __restrict__ src, us* __restrict__ dst,
                            int K, int N, int Ndst, long srcLS, long dstLS) {
  __shared__ float t[32][33];
  const int n0 = blockIdx.x << 5, k0 = blockIdx.y << 5;
  const int tx = threadIdx.x & 31, ty = threadIdx.x >> 5;
  const float* s = src + (size_t)blockIdx.z * srcLS;
  us* d = dst + (size_t)blockIdx.z * dstLS;
#pragma unroll
  for (int j = 0; j < 32; j += 8) {
    const int n = n0 + tx;
    t[ty + j][tx] = (n < N) ? s[(size_t)(k0 + ty + j) * N + n] : 0.f;
  }
  __syncthreads();
#pragma unroll
  for (int j = 0; j < 32; j += 8) {
    const int n = n0 + ty + j;
    if (n < Ndst) d[(size_t)n * K + k0 + tx] = f2bf(t[tx][ty + j]);
  }
}

// ---------------------------------------------------------------------------
// Async global->LDS staging of a ROWS x (CHPR*8 us) bf16 tile. LDS dest is
// linear; XOR chunk swizzle applied on the GLOBAL source side (rule #21).
// CHPR = 16B chunks per row (4 -> 64B rows, swz (row>>1)&3; 8 -> 128B rows,
// swz row&7). Read side must XOR the same way.
// ---------------------------------------------------------------------------
template<int ROWS, int CHPR>
__device__ __forceinline__ void stageG(const us* g, int rowUs, us* lds, int tid) {
#pragma unroll
  for (int j = 0; j < ROWS * CHPR / 256; ++j) {
    const int fl  = j * 256 + tid;
    const int row = fl / CHPR;
    const int c   = fl % CHPR;
    const int gc  = (CHPR == 8) ? (c ^ (row & 7)) : (c ^ ((row >> 1) & 3));
    const us* src = g + (size_t)row * rowUs + gc * 8;
    __builtin_amdgcn_global_load_lds(
        (const __attribute__((address_space(1))) u32*)src,
        (__attribute__((address_space(3))) u32*)(lds + ((fl >> 6) << 9)),
        16, 0, 0);
  }
}

// ---------------------------------------------------------------------------
// MFMA GEMM: C = A[M,K] @ Bt[N,K]^T. Tile (FM*32)x(FN*32), BK=32, 4 waves
// (2x2), per-wave FMxFN frags of 16x16x32_bf16. 3-buffer pipeline with
// counted vmcnt (never drains to 0 mid-loop) + raw s_barrier, 1 barrier/step.
// EPI: 0 = QKV split (q/k -> O0 [BT][768] bf16, v -> O1 [B*H][64][256] bf16)
//      1 = +bias +Res(fp32) -> fp32 O0
//      2 = +bias +ReLU -> bf16 O0
//      3 = +bias, col<65 -> fp32 O0 stride 65 (LM head)
// ---------------------------------------------------------------------------
template<int FM, int FN, int EPI>
__global__ __launch_bounds__(256)
void gemm_mfma(const us* __restrict__ A, const us* __restrict__ Bt,
               const float* __restrict__ bias, const float* Res,
               void* O0, void* O1, int N, int K, int gx) {
  constexpr int BM = FM * 32, BN = FN * 32;
  constexpr int LPS = BM / 64 + BN / 64;   // loads per thread per stage (A+B)
  __shared__ us As[3][BM * 32];
  __shared__ us Bs[3][BN * 32];
  const int tid = threadIdx.x;
  const int lid = xcd_swz(blockIdx.x, gridDim.x);
  const int bnI = lid % gx, bmI = lid / gx;
  const int bm = bmI * BM, bn = bnI * BN;
  const int wv = tid >> 6, ln = tid & 63;
  const int fm = ln & 15, fg = ln >> 4;
  const int wm = (wv >> 1) * (FM * 16), wn = (wv & 1) * (FN * 16);
  const us* Abase = A + (size_t)bm * K;
  const us* Bbase = Bt + (size_t)bn * K;

  f32x4 acc[FM][FN];
  const f32x4 zz = {0.f, 0.f, 0.f, 0.f};
#pragma unroll
  for (int i = 0; i < FM; ++i)
#pragma unroll
    for (int j = 0; j < FN; ++j) acc[i][j] = zz;

  const int NT = K >> 5;
  stageG<BM, 4>(Abase,      K, As[0], tid);
  stageG<BN, 4>(Bbase,      K, Bs[0], tid);
  stageG<BM, 4>(Abase + 32, K, As[1], tid);
  stageG<BN, 4>(Bbase + 32, K, Bs[1], tid);

  int cur = 0;
  for (int t = 0; t < NT; ++t) {
    if (t + 1 < NT) {
      asm volatile("s_waitcnt vmcnt(%0)" :: "n"(LPS) : "memory");
    } else {
      asm volatile("s_waitcnt vmcnt(0)" ::: "memory");
    }
    __builtin_amdgcn_s_barrier();
    __builtin_amdgcn_sched_barrier(0);
    if (t + 2 < NT) {
      const int nxt = (cur + 2 >= 3) ? cur - 1 : cur + 2;
      stageG<BM, 4>(Abase + (t + 2) * 32, K, As[nxt], tid);
      stageG<BN, 4>(Bbase + (t + 2) * 32, K, Bs[nxt], tid);
    }
    short8 af[FM], bfr[FN];
#pragma unroll
    for (int mt = 0; mt < FM; ++mt) {
      const int row = wm + mt * 16 + fm;
      af[mt] = *(const short8*)(As[cur] + row * 32 + ((fg ^ ((row >> 1) & 3)) << 3));
    }
#pragma unroll
    for (int nt = 0; nt < FN; ++nt) {
      const int row = wn + nt * 16 + fm;
      bfr[nt] = *(const short8*)(Bs[cur] + row * 32 + ((fg ^ ((row >> 1) & 3)) << 3));
    }
#pragma unroll
    for (int mt = 0; mt < FM; ++mt)
#pragma unroll
      for (int nt = 0; nt < FN; ++nt)
        acc[mt][nt] = __builtin_amdgcn_mfma_f32_16x16x32_bf16(af[mt], bfr[nt], acc[mt][nt], 0, 0, 0);
    cur = (cur + 1 == 3) ? 0 : cur + 1;
  }

  // ---- epilogue: lane holds rows fg*4+r, col fm of each 16x16 frag ----
#pragma unroll
  for (int mt = 0; mt < FM; ++mt) {
#pragma unroll
    for (int nt = 0; nt < FN; ++nt) {
      const int col  = bn + wn + nt * 16 + fm;
      const int row0 = bm + wm + mt * 16 + fg * 4;
      if (EPI == 0) {
        if (col < 768) {                      // q or k region
          us* qk = (us*)O0;
#pragma unroll
          for (int r = 0; r < 4; ++r)
            qk[(size_t)(row0 + r) * 768 + col] = f2bf(acc[mt][nt][r]);
        } else {                              // v -> transposed [B*H][64][256]
          const int d = col - 768;
          const int hh = d >> 6, dd = d & 63;
          const int bI = row0 >> 8, t0 = row0 & 255;
          us* vt = (us*)O1;
          ushort4 pk;
          pk.x = f2bf(acc[mt][nt][0]); pk.y = f2bf(acc[mt][nt][1]);
          pk.z = f2bf(acc[mt][nt][2]); pk.w = f2bf(acc[mt][nt][3]);
          *reinterpret_cast<ushort4*>(vt + ((size_t)((bI * H_ + hh) * 64 + dd)) * 256 + t0) = pk;
        }
      } else if (EPI == 1) {
        float* o = (float*)O0;
        const float bc = bias[col];
#pragma unroll
        for (int r = 0; r < 4; ++r) {
          const size_t idx = (size_t)(row0 + r) * N + col;
          o[idx] = acc[mt][nt][r] + bc + Res[idx];
        }
      } else if (EPI == 2) {
        us* o = (us*)O0;
        const float bc = bias[col];
#pragma unroll
        for (int r = 0; r < 4; ++r)
          o[(size_t)(row0 + r) * N + col] = f2bf(fmaxf(acc[mt][nt][r] + bc, 0.f));
      } else {
        if (col < V_) {
          float* o = (float*)O0;
          const float bc = bias[col];
#pragma unroll
          for (int r = 0; r < 4; ++r)
            o[(size_t)(row0 + r) * V_ + col] = acc[mt][nt][r] + bc;
        }
      }
    }
  }
}

// ---------------------------------------------------------------------------
// MFMA flash attention. Block = (b, h, 64-query tile); 4 waves x 16 queries.
// K/V tiles staged in LDS (double-buffered, issue-early 2-phase), CHPR=8
// XOR swizzle. qk: [BT][768] bf16; vT: [B*H][64][256] bf16; ab: [BT][384].
// ---------------------------------------------------------------------------
__global__ __launch_bounds__(256)
void attn_mfma(const us* __restrict__ qk, const us* __restrict__ vT,
               us* __restrict__ ab) {
  __shared__ us Ks[2][64 * 64];
  __shared__ us Vs[2][64 * 64];
  __shared__ us Plds[4][16 * 72];   // per-wave P tile, stride 72 (pad)
  const int tid = threadIdx.x, w = tid >> 6, l = tid & 63;
  const int m = l & 15, g = l >> 4;
  const int bi = xcd_swz(blockIdx.x, gridDim.x);
  const int b = bi / 24, rem = bi - b * 24, h = rem >> 2, qt = rem & 3;
  const int qrow = (b << 8) + (qt << 6) + (w << 4);
  const us* Kg = qk + (size_t)(b << 8) * 768 + 384 + h * 64;  // + kt*64 rows
  const us* Vg = vT + (size_t)(b * H_ + h) * 64 * 256;        // + kt*64 cols

  short8 qf0, qf1;
  {
    const us* qp = qk + (size_t)(qrow + m) * 768 + h * 64 + g * 8;
    qf0 = *(const short8*)qp;
    qf1 = *(const short8*)(qp + 32);
  }
  float mrow[4], ssum[4];
  f32x4 o[4];
  const f32x4 zz = {0.f, 0.f, 0.f, 0.f};
#pragma unroll
  for (int r = 0; r < 4; ++r) { mrow[r] = -1e30f; ssum[r] = 0.f; o[r] = zz; }

  stageG<64, 8>(Kg, 768, Ks[0], tid);
  stageG<64, 8>(Vg, 256, Vs[0], tid);
  __syncthreads();

  int cur = 0;
  for (int kt = 0; kt <= qt; ++kt) {
    if (kt < qt) {
      stageG<64, 8>(Kg + (size_t)(kt + 1) * 64 * 768, 768, Ks[cur ^ 1], tid);
      stageG<64, 8>(Vg + (kt + 1) * 64,               256, Vs[cur ^ 1], tid);
    }
    // ---- S = Q K^T (16 queries x 64 keys) from LDS ----
    f32x4 s[4];
#pragma unroll
    for (int nt = 0; nt < 4; ++nt) {
      const int row = nt * 16 + m;
      const int sw  = row & 7;
      short8 kf0 = *(const short8*)(Ks[cur] + row * 64 + ((g ^ sw) << 3));
      short8 kf1 = *(const short8*)(Ks[cur] + row * 64 + (((4 | g) ^ sw) << 3));
      f32x4 z = zz;
      z = __builtin_amdgcn_mfma_f32_16x16x32_bf16(qf0, kf0, z, 0, 0, 0);
      z = __builtin_amdgcn_mfma_f32_16x16x32_bf16(qf1, kf1, z, 0, 0, 0);
      s[nt] = z;
    }
    // ---- mask + online softmax ----
    const bool diag = (kt == qt);
    float p[4][4], tmax[4];
#pragma unroll
    for (int r = 0; r < 4; ++r) tmax[r] = -1e30f;
#pragma unroll
    for (int nt = 0; nt < 4; ++nt)
#pragma unroll
      for (int r = 0; r < 4; ++r) {
        float v = s[nt][r] * 0.125f;
        if (diag) {
          const int key = nt * 16 + m;
          const int qq  = (w << 4) + (g << 2) + r;
          if (key > qq) v = -1e30f;
        }
        p[nt][r] = v;
        tmax[r] = fmaxf(tmax[r], v);
      }
#pragma unroll
    for (int xm = 1; xm < 16; xm <<= 1)
#pragma unroll
      for (int r = 0; r < 4; ++r) tmax[r] = fmaxf(tmax[r], __shfl_xor(tmax[r], xm));
    float sc[4], tsum[4];
#pragma unroll
    for (int r = 0; r < 4; ++r) {
      const float nm = fmaxf(mrow[r], tmax[r]);
      sc[r] = __expf(mrow[r] - nm);
      mrow[r] = nm;
      tsum[r] = 0.f;
    }
#pragma unroll
    for (int nt = 0; nt < 4; ++nt)
#pragma unroll
      for (int r = 0; r < 4; ++r) {
        p[nt][r] = __expf(p[nt][r] - mrow[r]);
        tsum[r] += p[nt][r];
      }
#pragma unroll
    for (int xm = 1; xm < 16; xm <<= 1)
#pragma unroll
      for (int r = 0; r < 4; ++r) tsum[r] += __shfl_xor(tsum[r], xm);
#pragma unroll
    for (int r = 0; r < 4; ++r) ssum[r] = ssum[r] * sc[r] + tsum[r];
#pragma unroll
    for (int nt = 0; nt < 4; ++nt)
#pragma unroll
      for (int r = 0; r < 4; ++r) o[nt][r] *= sc[r];
    // ---- P -> LDS (bf16, C-layout -> A-layout transpose via LDS) ----
#pragma unroll
    for (int nt = 0; nt < 4; ++nt)
#pragma unroll
      for (int r = 0; r < 4; ++r)
        Plds[w][(g * 4 + r) * 72 + nt * 16 + m] = f2bf(p[nt][r]);
    // ---- O += P V (V from LDS) ----
#pragma unroll
    for (int kc = 0; kc < 2; ++kc) {
      short8 pa = *(const short8*)&Plds[w][m * 72 + kc * 32 + g * 8];
#pragma unroll
      for (int nd = 0; nd < 4; ++nd) {
        const int row = nd * 16 + m;
        short8 vf = *(const short8*)(Vs[cur] + row * 64 + ((((kc << 2) | g) ^ (row & 7)) << 3));
        o[nd] = __builtin_amdgcn_mfma_f32_16x16x32_bf16(pa, vf, o[nd], 0, 0, 0);
      }
    }
    __syncthreads();   // staged next tile arrived; all reads of cur done
    cur ^= 1;
  }
  // ---- normalize + write ----
#pragma unroll
  for (int r = 0; r < 4; ++r) {
    const float inv = 1.f / ssum[r];
    const size_t rowoff = (size_t)(qrow + g * 4 + r) * 384 + h * 64;
#pragma unroll
    for (int nd = 0; nd < 4; ++nd)
      ab[rowoff + nd * 16 + m] = f2bf(o[nd][r] * inv);
  }
}

// ---------------------------------------------------------------------------
extern "C" void kernel_launch(void* const* d_in, const int* in_sizes, int n_in,
                              void* d_out, int out_size, void* d_ws, size_t ws_size,
                              hipStream_t stream) {
  const int*   x    = (const int*)  d_in[0];
  const float* tok  = (const float*)d_in[1];
  const float* pos  = (const float*)d_in[2];
  const float* Wq   = (const float*)d_in[3];
  const float* Wk   = (const float*)d_in[4];
  const float* Wv   = (const float*)d_in[5];
  const float* Wpr  = (const float*)d_in[6];
  const float* bpr  = (const float*)d_in[7];
  const float* W1   = (const float*)d_in[8];
  const float* b1   = (const float*)d_in[9];
  const float* W2   = (const float*)d_in[10];
  const float* b2   = (const float*)d_in[11];
  const float* ln1g = (const float*)d_in[12];
  const float* ln1b = (const float*)d_in[13];
  const float* ln2g = (const float*)d_in[14];
  const float* ln2b = (const float*)d_in[15];
  const float* lnfg = (const float*)d_in[16];
  const float* lnfb = (const float*)d_in[17];
  const float* Wlm  = (const float*)d_in[18];
  const float* blm  = (const float*)d_in[19];
  float* out = (float*)d_out;

  char* W = (char*)d_ws;
  float* h    = (float*)(W + 0);               // [BT][384] fp32        25.2 MB
  us*    hn   = (us*)(W + 25165824);           // [BT][384] bf16        12.6 MB
  us*    qkb  = (us*)(W + 37748736);           // [BT][768] bf16        25.2 MB
  us*    vTb  = (us*)(W + 62914560);           // [B*H][64][256] bf16   12.6 MB
  us*    abb  = (us*)(W + 75497472);           // [BT][384] bf16        12.6 MB
  us*    ffa  = (us*)(W + 37748736);           // [BT][1536] bf16 (aliases qk+vT+ab)
  us*    qkvT = (us*)(W + 88080384);           // [L][1152][384] bf16
  us*    projT= (us*)(W + 93388800);           // [L][384][384]
  us*    W1T  = (us*)(W + 95158272);           // [L][1536][384]
  us*    W2T  = (us*)(W + 102236160);          // [L][384][1536]
  us*    WlmT = (us*)(W + 109314048);          // [128][384] (rows 65+ zero)

  // ---- weight conversion ----
  transpose_w<<<dim3(12,12,6), 256, 0, stream>>>(Wq,  qkvT,           384, 384, 384, 147456, 442368);
  transpose_w<<<dim3(12,12,6), 256, 0, stream>>>(Wk,  qkvT + 147456,  384, 384, 384, 147456, 442368);
  transpose_w<<<dim3(12,12,6), 256, 0, stream>>>(Wv,  qkvT + 294912,  384, 384, 384, 147456, 442368);
  transpose_w<<<dim3(12,12,6), 256, 0, stream>>>(Wpr, projT,          384, 384, 384, 147456, 147456);
  transpose_w<<<dim3(48,12,6), 256, 0, stream>>>(W1,  W1T,            384, 1536, 1536, 589824, 589824);
  transpose_w<<<dim3(12,48,6), 256, 0, stream>>>(W2,  W2T,            1536, 384, 384, 589824, 589824);
  transpose_w<<<dim3(4,12,1),  256, 0, stream>>>(Wlm, WlmT,           384, 65, 128, 0, 0);

  embed_kernel<<<2048, 256, 0, stream>>>(x, tok, pos, h);

  for (int l = 0; l < L_; ++l) {
    ln_kernel<1><<<BT_/4, 256, 0, stream>>>(h, hn, ln1g + l*E_, ln1b + l*E_);
    // QKV: N=1152, 128x128 tiles -> 9*128 = 1152 blocks
    gemm_mfma<4,4,0><<<1152, 256, 0, stream>>>(
        hn, qkvT + (size_t)l*442368, nullptr, nullptr, qkb, vTb, 1152, 384, 9);
    attn_mfma<<<B_*H_*4, 256, 0, stream>>>(qkb, vTb, abb);
    // proj: N=384, 64x128 tiles -> 3*256 = 768 blocks
    gemm_mfma<2,4,1><<<768, 256, 0, stream>>>(
        abb, projT + (size_t)l*147456, bpr + l*E_, h, h, nullptr, 384, 384, 3);
    ln_kernel<1><<<BT_/4, 256, 0, stream>>>(h, hn, ln2g + l*E_, ln2b + l*E_);
    // FF1: N=1536, 128x128 tiles -> 12*128 = 1536 blocks
    gemm_mfma<4,4,2><<<1536, 256, 0, stream>>>(
        hn, W1T + (size_t)l*589824, b1 + l*FF_, nullptr, ffa, nullptr, 1536, 384, 12);
    // FF2: N=384, K=1536, 64x128 tiles -> 768 blocks
    gemm_mfma<2,4,1><<<768, 256, 0, stream>>>(
        ffa, W2T + (size_t)l*589824, b2 + l*E_, h, h, nullptr, 384, 1536, 3);
  }

  ln_kernel<0><<<BT_/4, 256, 0, stream>>>(h, hn, lnfg, lnfb);
  // LM head: N=128(padded), 64x128 tiles -> 1*256 = 256 blocks
  gemm_mfma<2,4,3><<<256, 256, 0, stream>>>(
      hn, WlmT, blm, nullptr, out, nullptr, 128, 384, 1);
}